// Round 15
// baseline (376.912 us; speedup 1.0000x reference)
//
#include <hip/hip_runtime.h>
#include <math.h>

// Bahdanau attention, round 14: R12 (best, 318us) + T5 setprio around MFMA
// + dp/v prefetch hoist. R12 structure: phase 1 converts the 64x512 enc
// slice into a swizzled LDS tile (one barrier); phase 2 is a barrier-free
// K-loop (af from immutable LDS, bfr direct from fragment-ordered W2t).
// R12's waves have role diversity (cvt vs MFMA vs tanh) -> T5's regime.
//   ws: dp | W2t (fragment order) | pctx = 2.625 MiB

#define BATCH 64
#define SEQ   4096
#define HID   512

typedef __attribute__((ext_vector_type(8))) short bf16x8;
typedef __attribute__((ext_vector_type(4))) float f32x4;

__device__ __forceinline__ float fast_tanh(float x) {
    return 1.0f - 2.0f / (__expf(2.0f * x) + 1.0f);
}

__device__ __forceinline__ unsigned cvt2(float lo, float hi) {
    unsigned r;
    asm("v_cvt_pk_bf16_f32 %0, %1, %2" : "=v"(r) : "v"(lo), "v"(hi));
    return r;
}

// ---------------------------------------------------------------------------
// K0: W2 fp32 -> bf16 in MFMA fragment order (no gh split):
//   u16 index = kb*16384 + wn*2048 + fn*512 + rgl*128 + gl*8
// holds W2[g][k], g = wn*64 + fn*16 + gl, k = kb*32 + rgl*8 + j.
// ---------------------------------------------------------------------------
__global__ void k_cvtW2(const float* __restrict__ W2, ushort* __restrict__ W2t)
{
    const int n  = blockIdx.x * 256 + threadIdx.x;   // 0..32767
    const int g  = n >> 6, kc = n & 63;
    const int kb = kc >> 2, rgl = kc & 3;
    const int wn = g >> 6, fn = (g >> 4) & 3, gl = g & 15;

    const float* src = W2 + (size_t)g * HID + kc * 8;
    const float4 x = *reinterpret_cast<const float4*>(src);
    const float4 y = *reinterpret_cast<const float4*>(src + 4);
    uint4 u;
    u.x = cvt2(x.x, x.y);  u.y = cvt2(x.z, x.w);
    u.z = cvt2(y.x, y.y);  u.w = cvt2(y.z, y.w);

    const size_t dst = (size_t)kb * 16384 + wn * 2048 + fn * 512
                     + (rgl * 16 + gl) * 8;
    *reinterpret_cast<uint4*>(W2t + dst) = u;
}

// ---------------------------------------------------------------------------
// K1: dp[b][g] = sum_h dh[b][h] * W1[g][h]  (fp32, tiny)
// ---------------------------------------------------------------------------
__global__ void k_decproj(const float* __restrict__ dh,
                          const float* __restrict__ W1,
                          float* __restrict__ dp)
{
    __shared__ float wrow[HID];
    const int g = blockIdx.x;
    const int t = threadIdx.x;
    for (int i = t; i < HID; i += 256) wrow[i] = W1[g * HID + i];
    __syncthreads();

    const int b = t >> 2, q = t & 3;
    const float* dhb = dh + b * HID + q * 128;
    const float* wr  = wrow + q * 128;
    float acc = 0.f;
    #pragma unroll 8
    for (int i = 0; i < 128; i += 4) {
        const float4 d4 = *reinterpret_cast<const float4*>(dhb + i);
        acc = fmaf(d4.x, wr[i + 0], acc);
        acc = fmaf(d4.y, wr[i + 1], acc);
        acc = fmaf(d4.z, wr[i + 2], acc);
        acc = fmaf(d4.w, wr[i + 3], acc);
    }
    acc += __shfl_xor(acc, 1);
    acc += __shfl_xor(acc, 2);
    if (q == 0) dp[b * HID + g] = acc;
}

// ---------------------------------------------------------------------------
// K2: energy GEMM, phase-split (R12) + setprio.
// grid = 4096 (schunk = idx&63, b = idx>>6), 512 thr (8 waves).
// Phase 1: wave w converts rows {r*8+w}; lane l: 32B load -> cvt_pk -> 16B
//          ds_write at row*1024 + (l^(row&7))*16. One __syncthreads.
// Phase 2 (barrier-free): step kb: bfr 4x16B from W2t (L2), af 4x ds_read
//          from swizzled LDS, setprio(1), 16 MFMA, setprio(0).
// ---------------------------------------------------------------------------
__global__ __launch_bounds__(512, 2)
void k_energy(const float* __restrict__ enc, const ushort* __restrict__ W2t,
              const float* __restrict__ dp,  const float* __restrict__ v,
              float* __restrict__ energy)
{
    __shared__ __align__(16) ushort As[64 * 512];      // 64 KiB (swizzled)
    __shared__ float part[8][64];                      //  2 KiB

    const int idx    = blockIdx.x;
    const int schunk = idx & 63;
    const int b      = idx >> 6;
    const int s0     = schunk * 64;

    const int t    = threadIdx.x;
    const int lane = t & 63;
    const int w    = t >> 6;                   // wave 0..7 -> g block
    const int gl   = lane & 15, rg = lane >> 4;

    // ---- phase 1: convert enc slice into LDS ----
    #pragma unroll
    for (int r = 0; r < 8; ++r) {
        const int row = r * 8 + w;
        const float* rp = enc + ((size_t)(s0 + row) * BATCH + b) * HID + lane * 8;
        const float4 x = *reinterpret_cast<const float4*>(rp);
        const float4 y = *reinterpret_cast<const float4*>(rp + 4);
        uint4 u;
        u.x = cvt2(x.x, x.y);  u.y = cvt2(x.z, x.w);
        u.z = cvt2(y.x, y.y);  u.w = cvt2(y.z, y.w);
        const int slot = lane ^ (row & 7);
        *reinterpret_cast<uint4*>(
            reinterpret_cast<char*>(As) + row * 1024 + slot * 16) = u;
    }

    // hoist epilogue inputs: 16 K-steps of flight instead of epilogue stall
    float dpv[4], vv[4];
    #pragma unroll
    for (int n = 0; n < 4; ++n) {
        const int g = w * 64 + n * 16 + gl;
        dpv[n] = dp[b * HID + g];
        vv[n]  = v[g];
    }
    __syncthreads();

    // ---- phase 2: barrier-free K-loop ----
    f32x4 acc[4][4];
    const f32x4 z = {0.f, 0.f, 0.f, 0.f};
    #pragma unroll
    for (int m = 0; m < 4; ++m)
        #pragma unroll
        for (int n = 0; n < 4; ++n) acc[m][n] = z;

    const char* asbase = reinterpret_cast<const char*>(As) + gl * 1024;
    const char* bbase  = reinterpret_cast<const char*>(W2t)
                       + w * 4096 + lane * 16;
    const int   gmask  = gl & 7;

    #pragma unroll
    for (int kb = 0; kb < 16; ++kb) {
        bf16x8 bfr[4];
        const char* bstep = bbase + kb * 32768;
        #pragma unroll
        for (int n = 0; n < 4; ++n)
            bfr[n] = *reinterpret_cast<const bf16x8*>(bstep + n * 1024);

        const char* arow = asbase + ((4 * kb + rg) ^ gmask) * 16;
        bf16x8 af[4];
        #pragma unroll
        for (int m = 0; m < 4; ++m)
            af[m] = *reinterpret_cast<const bf16x8*>(arow + m * 16384);

        __builtin_amdgcn_s_setprio(1);
        #pragma unroll
        for (int m = 0; m < 4; ++m)
            #pragma unroll
            for (int n = 0; n < 4; ++n)
                acc[m][n] = __builtin_amdgcn_mfma_f32_16x16x32_bf16(
                    af[m], bfr[n], acc[m][n], 0, 0, 0);
        __builtin_amdgcn_s_setprio(0);
    }

    // ---- epilogue: energy over this block's full 512 g ----
    float p[4][4];
    #pragma unroll
    for (int m = 0; m < 4; ++m)
        #pragma unroll
        for (int r = 0; r < 4; ++r) p[m][r] = 0.f;
    #pragma unroll
    for (int n = 0; n < 4; ++n)
        #pragma unroll
        for (int m = 0; m < 4; ++m)
            #pragma unroll
            for (int r = 0; r < 4; ++r)
                p[m][r] += fast_tanh(dpv[n] + acc[m][n][r]) * vv[n];

    #pragma unroll
    for (int m = 0; m < 4; ++m)
        #pragma unroll
        for (int r = 0; r < 4; ++r) {
            float x = p[m][r];
            x += __shfl_xor(x, 1);
            x += __shfl_xor(x, 2);
            x += __shfl_xor(x, 4);
            x += __shfl_xor(x, 8);
            p[m][r] = x;
        }
    if (gl == 0) {
        #pragma unroll
        for (int m = 0; m < 4; ++m)
            #pragma unroll
            for (int r = 0; r < 4; ++r)
                part[w][m * 16 + rg * 4 + r] = p[m][r];
    }
    __syncthreads();

    if (t < 64) {
        float e = 0.f;
        #pragma unroll
        for (int q = 0; q < 8; ++q) e += part[q][t];
        energy[(size_t)b * SEQ + s0 + t] = e;
    }
}

// ---------------------------------------------------------------------------
// K3: softmax over s per b, IN PLACE on the attn region of d_out.
// ---------------------------------------------------------------------------
__global__ void k_softmax(float* __restrict__ attn)
{
    __shared__ float redm[4], reds[4];
    const int b = blockIdx.x, t = threadIdx.x;
    float* e = attn + (size_t)b * SEQ;

    float4 ev[4];
    float m = -3.4e38f;
    #pragma unroll
    for (int i = 0; i < 4; ++i) {
        ev[i] = *reinterpret_cast<const float4*>(e + i * 1024 + t * 4);
        m = fmaxf(m, fmaxf(fmaxf(ev[i].x, ev[i].y), fmaxf(ev[i].z, ev[i].w)));
    }
    #pragma unroll
    for (int off = 1; off < 64; off <<= 1) m = fmaxf(m, __shfl_xor(m, off));
    if ((t & 63) == 0) redm[t >> 6] = m;
    __syncthreads();
    m = fmaxf(fmaxf(redm[0], redm[1]), fmaxf(redm[2], redm[3]));

    float s = 0.f;
    #pragma unroll
    for (int i = 0; i < 4; ++i) {
        ev[i].x = __expf(ev[i].x - m);  ev[i].y = __expf(ev[i].y - m);
        ev[i].z = __expf(ev[i].z - m);  ev[i].w = __expf(ev[i].w - m);
        s += (ev[i].x + ev[i].y) + (ev[i].z + ev[i].w);
    }
    #pragma unroll
    for (int off = 1; off < 64; off <<= 1) s += __shfl_xor(s, off);
    if ((t & 63) == 0) reds[t >> 6] = s;
    __syncthreads();
    s = (reds[0] + reds[1]) + (reds[2] + reds[3]);
    const float inv = 1.0f / s;

    #pragma unroll
    for (int i = 0; i < 4; ++i) {
        const float4 w4 = make_float4(ev[i].x * inv, ev[i].y * inv,
                                      ev[i].z * inv, ev[i].w * inv);
        *reinterpret_cast<float4*>(e + i * 1024 + t * 4) = w4;
    }
}

// ---------------------------------------------------------------------------
// K4: partial context. grid = (64 b, 16 s-splits), 256 threads.
// ---------------------------------------------------------------------------
__global__ void k_ctxpart(const float* __restrict__ enc,
                          const float* __restrict__ attn,
                          float* __restrict__ pctx)
{
    __shared__ float w[256];
    const int b  = blockIdx.x;
    const int sp = blockIdx.y;
    const int t  = threadIdx.x;

    w[t] = attn[(size_t)b * SEQ + sp * 256 + t];
    __syncthreads();

    const float2* e2 = reinterpret_cast<const float2*>(enc);
    size_t idx = ((size_t)sp * 256 * BATCH + b) * (HID / 2) + t;
    const size_t stride = (size_t)BATCH * (HID / 2);

    float ax = 0.f, ay = 0.f;
    #pragma unroll 4
    for (int s = 0; s < 256; ++s) {
        const float2 ev = e2[idx];
        const float ws = w[s];
        ax = fmaf(ws, ev.x, ax);
        ay = fmaf(ws, ev.y, ay);
        idx += stride;
    }
    float2* p2 = reinterpret_cast<float2*>(pctx);
    p2[((size_t)sp * BATCH + b) * (HID / 2) + t] = make_float2(ax, ay);
}

// ---------------------------------------------------------------------------
// K5: context[b][h] = sum over 16 splits.
// ---------------------------------------------------------------------------
__global__ void k_ctxsum(const float* __restrict__ pctx,
                         float* __restrict__ ctx)
{
    const int i = blockIdx.x * 256 + threadIdx.x;
    float s = 0.f;
    #pragma unroll
    for (int sp = 0; sp < 16; ++sp) s += pctx[(size_t)sp * BATCH * HID + i];
    ctx[i] = s;
}

// ---------------------------------------------------------------------------
extern "C" void kernel_launch(void* const* d_in, const int* in_sizes, int n_in,
                              void* d_out, int out_size, void* d_ws, size_t ws_size,
                              hipStream_t stream)
{
    const float* dh  = (const float*)d_in[0];
    const float* enc = (const float*)d_in[1];
    const float* W1  = (const float*)d_in[2];
    const float* W2  = (const float*)d_in[3];
    const float* v   = (const float*)d_in[4];

    float* out  = (float*)d_out;
    float* ctx  = out;                           // 64*512
    float* attn = out + BATCH * HID;             // 64*4096 (energy -> softmax in place)

    float*  dp   = (float*)d_ws;                 // 128 KiB
    ushort* W2t  = (ushort*)(dp + BATCH * HID);  // 512 KiB (fragment order)
    float*  pctx = (float*)(W2t + HID * HID);    // 2 MiB

    k_cvtW2  <<<128, 256, 0, stream>>>(W2, W2t);
    k_decproj<<<HID, 256, 0, stream>>>(dh, W1, dp);
    k_energy <<<4096, 512, 0, stream>>>(enc, W2t, dp, v, attn);
    k_softmax<<<BATCH, 256, 0, stream>>>(attn);
    k_ctxpart<<<dim3(BATCH, 16), 256, 0, stream>>>(enc, attn, pctx);
    k_ctxsum <<<BATCH * HID / 256, 256, 0, stream>>>(pctx, ctx);
}

// Round 16
// 319.124 us; speedup vs baseline: 1.1811x; 1.1811x over previous
//
#include <hip/hip_runtime.h>
#include <math.h>

// Bahdanau attention, round 15: R12 + per-wave K-phase rotation.
// The ~250us k_energy plateau matches an unoverlapped per-step chain with
// all waves in lockstep (same W2t slab, same completion time, same MFMA
// burst). K-accumulation is commutative -> each wave walks the K-steps in a
// rotated order (kstep = (kb+phase)&15). Waves touch different B slabs at
// any instant and dephase structurally. Only change vs R12.
//   ws: dp | W2t (fragment order) | pctx = 2.625 MiB

#define BATCH 64
#define SEQ   4096
#define HID   512

typedef __attribute__((ext_vector_type(8))) short bf16x8;
typedef __attribute__((ext_vector_type(4))) float f32x4;

__device__ __forceinline__ float fast_tanh(float x) {
    return 1.0f - 2.0f / (__expf(2.0f * x) + 1.0f);
}

__device__ __forceinline__ unsigned cvt2(float lo, float hi) {
    unsigned r;
    asm("v_cvt_pk_bf16_f32 %0, %1, %2" : "=v"(r) : "v"(lo), "v"(hi));
    return r;
}

// ---------------------------------------------------------------------------
// K0: W2 fp32 -> bf16 in MFMA fragment order (no gh split):
//   u16 index = kb*16384 + wn*2048 + fn*512 + rgl*128 + gl*8
// holds W2[g][k], g = wn*64 + fn*16 + gl, k = kb*32 + rgl*8 + j.
// ---------------------------------------------------------------------------
__global__ void k_cvtW2(const float* __restrict__ W2, ushort* __restrict__ W2t)
{
    const int n  = blockIdx.x * 256 + threadIdx.x;   // 0..32767
    const int g  = n >> 6, kc = n & 63;
    const int kb = kc >> 2, rgl = kc & 3;
    const int wn = g >> 6, fn = (g >> 4) & 3, gl = g & 15;

    const float* src = W2 + (size_t)g * HID + kc * 8;
    const float4 x = *reinterpret_cast<const float4*>(src);
    const float4 y = *reinterpret_cast<const float4*>(src + 4);
    uint4 u;
    u.x = cvt2(x.x, x.y);  u.y = cvt2(x.z, x.w);
    u.z = cvt2(y.x, y.y);  u.w = cvt2(y.z, y.w);

    const size_t dst = (size_t)kb * 16384 + wn * 2048 + fn * 512
                     + (rgl * 16 + gl) * 8;
    *reinterpret_cast<uint4*>(W2t + dst) = u;
}

// ---------------------------------------------------------------------------
// K1: dp[b][g] = sum_h dh[b][h] * W1[g][h]  (fp32, tiny)
// ---------------------------------------------------------------------------
__global__ void k_decproj(const float* __restrict__ dh,
                          const float* __restrict__ W1,
                          float* __restrict__ dp)
{
    __shared__ float wrow[HID];
    const int g = blockIdx.x;
    const int t = threadIdx.x;
    for (int i = t; i < HID; i += 256) wrow[i] = W1[g * HID + i];
    __syncthreads();

    const int b = t >> 2, q = t & 3;
    const float* dhb = dh + b * HID + q * 128;
    const float* wr  = wrow + q * 128;
    float acc = 0.f;
    #pragma unroll 8
    for (int i = 0; i < 128; i += 4) {
        const float4 d4 = *reinterpret_cast<const float4*>(dhb + i);
        acc = fmaf(d4.x, wr[i + 0], acc);
        acc = fmaf(d4.y, wr[i + 1], acc);
        acc = fmaf(d4.z, wr[i + 2], acc);
        acc = fmaf(d4.w, wr[i + 3], acc);
    }
    acc += __shfl_xor(acc, 1);
    acc += __shfl_xor(acc, 2);
    if (q == 0) dp[b * HID + g] = acc;
}

// ---------------------------------------------------------------------------
// K2: energy GEMM, phase-split + K-phase rotation.
// grid = 4096 (schunk = idx&63, b = idx>>6), 512 thr (8 waves).
// Phase 1: wave w converts rows {r*8+w}; lane l: 32B load -> cvt_pk -> 16B
//          ds_write at row*1024 + (l^(row&7))*16. One __syncthreads.
// Phase 2 (barrier-free): iteration kb computes K-step (kb+phase)&15 with
//          phase = (w*2 + (idx&1)) & 15 -- commutative accumulation, so
//          order is free; waves hit distinct B slabs and dephase.
// ---------------------------------------------------------------------------
__global__ __launch_bounds__(512, 2)
void k_energy(const float* __restrict__ enc, const ushort* __restrict__ W2t,
              const float* __restrict__ dp,  const float* __restrict__ v,
              float* __restrict__ energy)
{
    __shared__ __align__(16) ushort As[64 * 512];      // 64 KiB (swizzled)
    __shared__ float part[8][64];                      //  2 KiB

    const int idx    = blockIdx.x;
    const int schunk = idx & 63;
    const int b      = idx >> 6;
    const int s0     = schunk * 64;

    const int t    = threadIdx.x;
    const int lane = t & 63;
    const int w    = t >> 6;                   // wave 0..7 -> g block
    const int gl   = lane & 15, rg = lane >> 4;

    // ---- phase 1: convert enc slice into LDS ----
    #pragma unroll
    for (int r = 0; r < 8; ++r) {
        const int row = r * 8 + w;
        const float* rp = enc + ((size_t)(s0 + row) * BATCH + b) * HID + lane * 8;
        const float4 x = *reinterpret_cast<const float4*>(rp);
        const float4 y = *reinterpret_cast<const float4*>(rp + 4);
        uint4 u;
        u.x = cvt2(x.x, x.y);  u.y = cvt2(x.z, x.w);
        u.z = cvt2(y.x, y.y);  u.w = cvt2(y.z, y.w);
        const int slot = lane ^ (row & 7);
        *reinterpret_cast<uint4*>(
            reinterpret_cast<char*>(As) + row * 1024 + slot * 16) = u;
    }
    __syncthreads();

    // ---- phase 2: barrier-free K-loop, rotated K order ----
    f32x4 acc[4][4];
    const f32x4 z = {0.f, 0.f, 0.f, 0.f};
    #pragma unroll
    for (int m = 0; m < 4; ++m)
        #pragma unroll
        for (int n = 0; n < 4; ++n) acc[m][n] = z;

    const char* asbase = reinterpret_cast<const char*>(As) + gl * 1024;
    const char* bbase  = reinterpret_cast<const char*>(W2t)
                       + w * 4096 + lane * 16;
    const int   gmask  = gl & 7;
    const int   phase  = (w * 2 + (idx & 1)) & 15;

    #pragma unroll
    for (int kb = 0; kb < 16; ++kb) {
        const int kstep = (kb + phase) & 15;

        bf16x8 bfr[4];
        const char* bstep = bbase + kstep * 32768;     // SALU-uniform
        #pragma unroll
        for (int n = 0; n < 4; ++n)
            bfr[n] = *reinterpret_cast<const bf16x8*>(bstep + n * 1024);

        const char* arow = asbase + ((4 * kstep + rg) ^ gmask) * 16;
        bf16x8 af[4];
        #pragma unroll
        for (int m = 0; m < 4; ++m)
            af[m] = *reinterpret_cast<const bf16x8*>(arow + m * 16384);

        #pragma unroll
        for (int m = 0; m < 4; ++m)
            #pragma unroll
            for (int n = 0; n < 4; ++n)
                acc[m][n] = __builtin_amdgcn_mfma_f32_16x16x32_bf16(
                    af[m], bfr[n], acc[m][n], 0, 0, 0);
    }

    // ---- epilogue: energy over this block's full 512 g ----
    float dpv[4], vv[4];
    #pragma unroll
    for (int n = 0; n < 4; ++n) {
        const int g = w * 64 + n * 16 + gl;
        dpv[n] = dp[b * HID + g];
        vv[n]  = v[g];
    }
    float p[4][4];
    #pragma unroll
    for (int m = 0; m < 4; ++m)
        #pragma unroll
        for (int r = 0; r < 4; ++r) p[m][r] = 0.f;
    #pragma unroll
    for (int n = 0; n < 4; ++n)
        #pragma unroll
        for (int m = 0; m < 4; ++m)
            #pragma unroll
            for (int r = 0; r < 4; ++r)
                p[m][r] += fast_tanh(dpv[n] + acc[m][n][r]) * vv[n];

    #pragma unroll
    for (int m = 0; m < 4; ++m)
        #pragma unroll
        for (int r = 0; r < 4; ++r) {
            float x = p[m][r];
            x += __shfl_xor(x, 1);
            x += __shfl_xor(x, 2);
            x += __shfl_xor(x, 4);
            x += __shfl_xor(x, 8);
            p[m][r] = x;
        }
    if (gl == 0) {
        #pragma unroll
        for (int m = 0; m < 4; ++m)
            #pragma unroll
            for (int r = 0; r < 4; ++r)
                part[w][m * 16 + rg * 4 + r] = p[m][r];
    }
    __syncthreads();

    if (t < 64) {
        float e = 0.f;
        #pragma unroll
        for (int q = 0; q < 8; ++q) e += part[q][t];
        energy[(size_t)b * SEQ + s0 + t] = e;
    }
}

// ---------------------------------------------------------------------------
// K3: softmax over s per b, IN PLACE on the attn region of d_out.
// ---------------------------------------------------------------------------
__global__ void k_softmax(float* __restrict__ attn)
{
    __shared__ float redm[4], reds[4];
    const int b = blockIdx.x, t = threadIdx.x;
    float* e = attn + (size_t)b * SEQ;

    float4 ev[4];
    float m = -3.4e38f;
    #pragma unroll
    for (int i = 0; i < 4; ++i) {
        ev[i] = *reinterpret_cast<const float4*>(e + i * 1024 + t * 4);
        m = fmaxf(m, fmaxf(fmaxf(ev[i].x, ev[i].y), fmaxf(ev[i].z, ev[i].w)));
    }
    #pragma unroll
    for (int off = 1; off < 64; off <<= 1) m = fmaxf(m, __shfl_xor(m, off));
    if ((t & 63) == 0) redm[t >> 6] = m;
    __syncthreads();
    m = fmaxf(fmaxf(redm[0], redm[1]), fmaxf(redm[2], redm[3]));

    float s = 0.f;
    #pragma unroll
    for (int i = 0; i < 4; ++i) {
        ev[i].x = __expf(ev[i].x - m);  ev[i].y = __expf(ev[i].y - m);
        ev[i].z = __expf(ev[i].z - m);  ev[i].w = __expf(ev[i].w - m);
        s += (ev[i].x + ev[i].y) + (ev[i].z + ev[i].w);
    }
    #pragma unroll
    for (int off = 1; off < 64; off <<= 1) s += __shfl_xor(s, off);
    if ((t & 63) == 0) reds[t >> 6] = s;
    __syncthreads();
    s = (reds[0] + reds[1]) + (reds[2] + reds[3]);
    const float inv = 1.0f / s;

    #pragma unroll
    for (int i = 0; i < 4; ++i) {
        const float4 w4 = make_float4(ev[i].x * inv, ev[i].y * inv,
                                      ev[i].z * inv, ev[i].w * inv);
        *reinterpret_cast<float4*>(e + i * 1024 + t * 4) = w4;
    }
}

// ---------------------------------------------------------------------------
// K4: partial context. grid = (64 b, 16 s-splits), 256 threads.
// ---------------------------------------------------------------------------
__global__ void k_ctxpart(const float* __restrict__ enc,
                          const float* __restrict__ attn,
                          float* __restrict__ pctx)
{
    __shared__ float w[256];
    const int b  = blockIdx.x;
    const int sp = blockIdx.y;
    const int t  = threadIdx.x;

    w[t] = attn[(size_t)b * SEQ + sp * 256 + t];
    __syncthreads();

    const float2* e2 = reinterpret_cast<const float2*>(enc);
    size_t idx = ((size_t)sp * 256 * BATCH + b) * (HID / 2) + t;
    const size_t stride = (size_t)BATCH * (HID / 2);

    float ax = 0.f, ay = 0.f;
    #pragma unroll 4
    for (int s = 0; s < 256; ++s) {
        const float2 ev = e2[idx];
        const float ws = w[s];
        ax = fmaf(ws, ev.x, ax);
        ay = fmaf(ws, ev.y, ay);
        idx += stride;
    }
    float2* p2 = reinterpret_cast<float2*>(pctx);
    p2[((size_t)sp * BATCH + b) * (HID / 2) + t] = make_float2(ax, ay);
}

// ---------------------------------------------------------------------------
// K5: context[b][h] = sum over 16 splits.
// ---------------------------------------------------------------------------
__global__ void k_ctxsum(const float* __restrict__ pctx,
                         float* __restrict__ ctx)
{
    const int i = blockIdx.x * 256 + threadIdx.x;
    float s = 0.f;
    #pragma unroll
    for (int sp = 0; sp < 16; ++sp) s += pctx[(size_t)sp * BATCH * HID + i];
    ctx[i] = s;
}

// ---------------------------------------------------------------------------
extern "C" void kernel_launch(void* const* d_in, const int* in_sizes, int n_in,
                              void* d_out, int out_size, void* d_ws, size_t ws_size,
                              hipStream_t stream)
{
    const float* dh  = (const float*)d_in[0];
    const float* enc = (const float*)d_in[1];
    const float* W1  = (const float*)d_in[2];
    const float* W2  = (const float*)d_in[3];
    const float* v   = (const float*)d_in[4];

    float* out  = (float*)d_out;
    float* ctx  = out;                           // 64*512
    float* attn = out + BATCH * HID;             // 64*4096 (energy -> softmax in place)

    float*  dp   = (float*)d_ws;                 // 128 KiB
    ushort* W2t  = (ushort*)(dp + BATCH * HID);  // 512 KiB (fragment order)
    float*  pctx = (float*)(W2t + HID * HID);    // 2 MiB

    k_cvtW2  <<<128, 256, 0, stream>>>(W2, W2t);
    k_decproj<<<HID, 256, 0, stream>>>(dh, W1, dp);
    k_energy <<<4096, 512, 0, stream>>>(enc, W2t, dp, v, attn);
    k_softmax<<<BATCH, 256, 0, stream>>>(attn);
    k_ctxpart<<<dim3(BATCH, 16), 256, 0, stream>>>(enc, attn, pctx);
    k_ctxsum <<<BATCH * HID / 256, 256, 0, stream>>>(pctx, ctx);
}